// Round 2
// baseline (231.117 us; speedup 1.0000x reference)
//
#include <hip/hip_runtime.h>

// CRF NLL: B=1024, S=512, T=48.  ONE wave per batch element (1024x64).
// R6: R4 skeleton (two sequential halves F then B per jiter, lane j owns
// state j) but the state broadcast goes through SGPRs instead of LDS:
//   publish: cvt f16 -> pair with xor-1 neighbor (DPP shuffle, no LDS)
//            -> v_readlane the 24 even lanes into 24 SGPR u32s.
//   consume: v_dot2_f32_f16 with the state pair as the (legal, single)
//            SGPR operand and per-lane E' fragments in VGPRs.
// This removes every DS op from the recurrence: R5 proved the kernel is
// latency-bound (halving LDS traffic didn't help, VALUBusy 22%, 1
// wave/SIMD), so the ~660 stall cyc/jiter must be the LDS write->read
// round-trip + lgkmcnt ordering.  readlane has no memory latency.
// E' = exp(trans) * 2^-8 folded scale keeps f16 values in range;
// exact pow2 probe-rescale every 4 iters; publish clamped at 60000.

#define T 48
#define SLEN 512
#define BATCH 1024

typedef _Float16 h2 __attribute__((ext_vector_type(2)));

__device__ __forceinline__ float wave_sum(float v) {
#pragma unroll
    for (int m = 32; m >= 1; m >>= 1) v += __shfl_xor(v, m, 64);
    return v;
}
__device__ __forceinline__ float wave_max(float v) {
#pragma unroll
    for (int m = 32; m >= 1; m >>= 1) v = fmaxf(v, __shfl_xor(v, m, 64));
    return v;
}
__device__ __forceinline__ float rlane(float v, int k) {
    return __int_as_float(__builtin_amdgcn_readlane(__float_as_int(v), k));
}
__device__ __forceinline__ float fdot2(h2 a, h2 b, float c) {
#if __has_builtin(__builtin_amdgcn_fdot2)
    return __builtin_amdgcn_fdot2(a, b, c, false);
#else
    return fmaf((float)a[1], (float)b[1], fmaf((float)a[0], (float)b[0], c));
#endif
}

// state pair k as h2 from the SGPR array
#define QH(S, k) (__builtin_bit_cast(h2, (S)[k]))

// 48-long dot: 24 fdot2 into 4 accumulator chains (depth 6 each)
#define DOTS48(S, E, A0, A1, A2, A3)                 \
    _Pragma("unroll")                                \
    for (int t = 0; t < 24; t += 4) {                \
        A0 = fdot2(QH(S, t + 0), E[t + 0], A0);      \
        A1 = fdot2(QH(S, t + 1), E[t + 1], A1);      \
        A2 = fdot2(QH(S, t + 2), E[t + 2], A2);      \
        A3 = fdot2(QH(S, t + 3), E[t + 3], A3);      \
    }

// publish: lane j holds state value VAL (f32, already clamped/scaled);
// cvt to f16 (RTE, matches R4 numerics), pack (even,odd) pairs via xor-1
// neighbor exchange, readlane even lanes 0..46 into DST[0..23] (SGPRs).
#define BCAST24(DST, VAL)                                                 \
    {                                                                     \
        unsigned hp_ = (unsigned)__builtin_bit_cast(unsigned short,       \
                          (_Float16)(VAL));                               \
        unsigned op_ = __shfl_xor(hp_, 1, 64);                            \
        unsigned lo_ = (lane & 1) ? op_ : hp_;                            \
        unsigned hi_ = (lane & 1) ? hp_ : op_;                            \
        unsigned pk_ = lo_ | (hi_ << 16);                                 \
        _Pragma("unroll")                                                 \
        for (int k = 0; k < 24; ++k)                                      \
            (DST)[k] = (unsigned)__builtin_amdgcn_readlane((int)pk_,      \
                                                            2 * k);       \
    }

__global__ __launch_bounds__(64) void crf_kernel(
    const float* __restrict__ em,      // (B,S,T)
    const int*   __restrict__ tags,    // (B,S)
    const float* __restrict__ mask,    // (B,S)
    const float* __restrict__ trans,   // (T,T)
    const float* __restrict__ start_t, // (T,)
    const float* __restrict__ end_t,   // (T,)
    float*       __restrict__ out)     // scalar
{
    constexpr float LOG2E = 1.4426950408889634f;
    constexpr float LN2   = 0.6931471805599453f;
    constexpr float ESC   = -8.0f;     // fold 2^-8 into E' for f16 range

    const int b    = blockIdx.x;
    const int lane = threadIdx.x;
    const int j    = lane < T ? lane : (T - 1);

    const float* em_b   = em   + (size_t)b * SLEN * T;
    const float* mask_b = mask + (size_t)b * SLEN;
    const int*   tags_b = tags + (size_t)b * SLEN;

    // ---- sequence length ----
    float msum = 0.f;
    for (int s = lane; s < SLEN; s += 64) msum += mask_b[s];
    msum = wave_sum(msum);
    const int len = (int)(msum + 0.5f);
    const int nb  = (len - 1) >> 1;           // bwd steps (joint iters)
    const int nf  = (len - 1) - nb;           // fwd steps = nb or nb+1

    // ---- gold path score ----
    float g = 0.f;
    for (int i = lane; i < len; i += 64) {
        if (i >= 1) {
            const int tc = tags_b[i];
            const int tp = tags_b[i - 1];
            g += trans[tc * T + tp] + em_b[(size_t)i * T + tc];
        }
    }
    g = wave_sum(g);

    // ---- packed E' fragments: col j (fwd) and row j (bwd), pairs over k ----
    h2 Ec[24], Er[24];
#pragma unroll
    for (int k = 0; k < T; k += 2) {
        h2 c, r;
        c[0] = (_Float16)exp2f(trans[(k    ) * T + j] * LOG2E + ESC);
        c[1] = (_Float16)exp2f(trans[(k + 1) * T + j] * LOG2E + ESC);
        r[0] = (_Float16)exp2f(trans[j * T + (k    )] * LOG2E + ESC);
        r[1] = (_Float16)exp2f(trans[j * T + (k + 1)] * LOG2E + ESC);
        Ec[k >> 1] = c; Er[k >> 1] = r;
    }

    // ---- init ----
    const float z0 = (start_t[j] + em_b[j]) * LOG2E;
    const float m0 = wave_max(z0);
    float pf = exp2f(z0 - m0);
    float u  = exp2f(end_t[j] * LOG2E);
    float Lf = m0, Lb = 0.f;

    const float* ep = em_b + j;
    const int maxoff = (SLEN - 1) * T;

    // emissions needed at known one-off positions (prefetch now)
    const float vlast  = ep[(size_t)(len - 1) * T];   // bwd init weight
    const float vextra = ep[(size_t)nf * T];          // extra fwd step weight

    // state broadcast registers (wave-uniform -> SGPRs)
    unsigned sf[24], sb[24];
    BCAST24(sf, pf)
    BCAST24(sb, fminf(u * exp2f(vlast * LOG2E), 60000.f))

    // emission rings (4 deep each)
    int fo = T;
    float f0 = ep[fo < maxoff ? fo : maxoff]; fo += T;
    float f1 = ep[fo < maxoff ? fo : maxoff]; fo += T;
    float f2 = ep[fo < maxoff ? fo : maxoff]; fo += T;
    float f3 = ep[fo < maxoff ? fo : maxoff]; fo += T;
    int bo = (len - 2) * T;
    float e0 = ep[bo > 0 ? bo : 0]; bo -= T;
    float e1 = ep[bo > 0 ? bo : 0]; bo -= T;
    float e2 = ep[bo > 0 ? bo : 0]; bo -= T;
    float e3 = ep[bo > 0 ? bo : 0]; bo -= T;

    auto rescale = [&](float& v, float& L) {   // exact pow2, 4-lane probe
        float m = fmaxf(fmaxf(rlane(v, 0), rlane(v, 16)),
                        fmaxf(rlane(v, 32), rlane(v, 47)));
        int e = ((__float_as_int(m) >> 23) & 255) - 127;
        e = e < -64 ? -64 : e;
        v *= __int_as_float((127 - e) << 23);
        L += (float)e;
    };

    auto jiter = [&](float& fe, float& be, bool resc) {
        // ---- forward half: consume sf (SGPR state), publish new sf
        float wf = exp2f(fe * LOG2E);
        fe = ep[fo < maxoff ? fo : maxoff]; fo += T;
        float a0=0.f, a1=0.f, a2=0.f, a3=0.f;
        DOTS48(sf, Ec, a0, a1, a2, a3)
        float pn = ((a0 + a1) + (a2 + a3)) * wf;
        if (resc) rescale(pn, Lf);
        pf = pn;
        BCAST24(sf, fminf(pn, 60000.f))
        // ---- backward half
        float wb = exp2f(be * LOG2E);
        be = ep[bo > 0 ? bo : 0]; bo -= T;
        float c0=0.f, c1=0.f, c2=0.f, c3=0.f;
        DOTS48(sb, Er, c0, c1, c2, c3)
        float un = (c0 + c1) + (c2 + c3);
        if (resc) rescale(un, Lb);
        u = un;
        BCAST24(sb, fminf(un * wb, 60000.f))
    };

    int rem = nb;
    while (rem >= 4) {
        jiter(f0, e0, false);
        jiter(f1, e1, false);
        jiter(f2, e2, false);
        jiter(f3, e3, true);
        rem -= 4;
    }
    if (rem > 0) { jiter(f0, e0, false);
        if (rem > 1) { jiter(f1, e1, false);
            if (rem > 2) jiter(f2, e2, false); } }

    // ---- extra forward step (nf = nb+1 case); sf holds p_nb ----
    if (nf > nb) {
        float wf = exp2f(vextra * LOG2E);
        float a0=0.f, a1=0.f, a2=0.f, a3=0.f;
        DOTS48(sf, Ec, a0, a1, a2, a3)
        pf = ((a0 + a1) + (a2 + a3)) * wf;
    }

    // ---- finalize: undo folded 2^-8 per step, combine at m = nf ----
    Lf += 8.0f * (float)nf;
    Lb += 8.0f * (float)nb;
    const float v  = (lane < T) ? pf * u : 0.f;
    const float S_ = wave_sum(v);
    const float fwd = (Lf + Lb + log2f(S_)) * LN2;

    if (lane == 0) {
        const int t0 = tags_b[0];
        const int tl = tags_b[len - 1];
        const float gold = g + start_t[t0] + em_b[t0] + end_t[tl];
        atomicAdd(out, (fwd - gold) * (1.0f / (float)BATCH));
    }
}

extern "C" void kernel_launch(void* const* d_in, const int* in_sizes, int n_in,
                              void* d_out, int out_size, void* d_ws, size_t ws_size,
                              hipStream_t stream) {
    const float* em      = (const float*)d_in[0];
    const int*   tags    = (const int*)  d_in[1];
    const float* mask    = (const float*)d_in[2];
    const float* trans   = (const float*)d_in[3];
    const float* start_t = (const float*)d_in[4];
    const float* end_t   = (const float*)d_in[5];
    float* out = (float*)d_out;

    hipMemsetAsync(out, 0, sizeof(float), stream);
    crf_kernel<<<BATCH, 64, 0, stream>>>(em, tags, mask, trans, start_t, end_t, out);
}

// Round 3
// 222.648 us; speedup vs baseline: 1.0380x; 1.0380x over previous
//
#include <hip/hip_runtime.h>

// CRF NLL: B=1024, S=512, T=48.
// R7: split the fwd and bwd chains into SEPARATE waves (block = 128 thr =
// 2 waves, wave0 = forward alpha chain, wave1 = backward beta chain).
// R5/R6 proved the kernel is dependent-issue-latency bound at 1 wave/SIMD:
// removing LDS entirely still left ~700 stall cyc/jiter (VALUBusy 31%).
// Splitting chains (a) halves the serial work per step of the critical
// wave (one 48-dot + one broadcast instead of two), and (b) doubles
// occupancy to 2 waves/SIMD so HW round-robin fills the dependence
// bubbles via TLP.  Chains meet at position nf; Z is combined in-block
// through LDS + one __syncthreads (no workspace, no 2nd kernel).
// Per-step math is byte-identical to the proven path: f16 state broadcast
// via v_readlane SGPRs, E' = exp(trans)*2^-8 f16, dest-weight on fwd /
// publish-weight on bwd, exact pow2 probe-rescale every 4 steps, 60000
// clamp on published values.

#define T 48
#define SLEN 512
#define BATCH 1024

typedef _Float16 h2 __attribute__((ext_vector_type(2)));

__device__ __forceinline__ float wave_sum(float v) {
#pragma unroll
    for (int m = 32; m >= 1; m >>= 1) v += __shfl_xor(v, m, 64);
    return v;
}
__device__ __forceinline__ float wave_max(float v) {
#pragma unroll
    for (int m = 32; m >= 1; m >>= 1) v = fmaxf(v, __shfl_xor(v, m, 64));
    return v;
}
__device__ __forceinline__ float rlane(float v, int k) {
    return __int_as_float(__builtin_amdgcn_readlane(__float_as_int(v), k));
}
__device__ __forceinline__ float fdot2(h2 a, h2 b, float c) {
#if __has_builtin(__builtin_amdgcn_fdot2)
    return __builtin_amdgcn_fdot2(a, b, c, false);
#else
    return fmaf((float)a[1], (float)b[1], fmaf((float)a[0], (float)b[0], c));
#endif
}

// state pair k as h2 from the SGPR array
#define QH(S, k) (__builtin_bit_cast(h2, (S)[k]))

// 48-long dot: 24 fdot2 into 4 accumulator chains (depth 6 each)
#define DOTS48(S, E, A0, A1, A2, A3)                 \
    _Pragma("unroll")                                \
    for (int t = 0; t < 24; t += 4) {                \
        A0 = fdot2(QH(S, t + 0), E[t + 0], A0);      \
        A1 = fdot2(QH(S, t + 1), E[t + 1], A1);      \
        A2 = fdot2(QH(S, t + 2), E[t + 2], A2);      \
        A3 = fdot2(QH(S, t + 3), E[t + 3], A3);      \
    }

// publish: lane j holds state value VAL (f32, already clamped/scaled);
// cvt to f16 (RTE), pack (even,odd) pairs via xor-1 neighbor exchange,
// readlane even lanes 0..46 into DST[0..23] (wave-uniform -> SGPRs).
#define BCAST24(DST, VAL)                                                 \
    {                                                                     \
        unsigned hp_ = (unsigned)__builtin_bit_cast(unsigned short,       \
                          (_Float16)(VAL));                               \
        unsigned op_ = __shfl_xor(hp_, 1, 64);                            \
        unsigned lo_ = (lane & 1) ? op_ : hp_;                            \
        unsigned hi_ = (lane & 1) ? hp_ : op_;                            \
        unsigned pk_ = lo_ | (hi_ << 16);                                 \
        _Pragma("unroll")                                                 \
        for (int k = 0; k < 24; ++k)                                      \
            (DST)[k] = (unsigned)__builtin_amdgcn_readlane((int)pk_,      \
                                                            2 * k);       \
    }

__global__ __launch_bounds__(128) void crf_kernel(
    const float* __restrict__ em,      // (B,S,T)
    const int*   __restrict__ tags,    // (B,S)
    const float* __restrict__ mask,    // (B,S)
    const float* __restrict__ trans,   // (T,T)
    const float* __restrict__ start_t, // (T,)
    const float* __restrict__ end_t,   // (T,)
    float*       __restrict__ out)     // scalar
{
    constexpr float LOG2E = 1.4426950408889634f;
    constexpr float LN2   = 0.6931471805599453f;
    constexpr float ESC   = -8.0f;     // fold 2^-8 into E' for f16 range

    const int b    = blockIdx.x;
    const int tid  = threadIdx.x;
    const int w    = tid >> 6;         // 0 = forward chain, 1 = backward
    const int lane = tid & 63;
    const int j    = lane < T ? lane : (T - 1);

    const float* em_b   = em   + (size_t)b * SLEN * T;
    const float* mask_b = mask + (size_t)b * SLEN;
    const int*   tags_b = tags + (size_t)b * SLEN;

    // ---- sequence length (each wave for itself) ----
    float msum = 0.f;
    for (int s = lane; s < SLEN; s += 64) msum += mask_b[s];
    msum = wave_sum(msum);
    const int len = (int)(msum + 0.5f);
    const int nb  = (len - 1) >> 1;           // bwd steps
    const int nf  = (len - 1) - nb;           // fwd steps = nb or nb+1
    const int steps = w ? nb : nf;

    // ---- packed E' fragments: wave0 col j, wave1 row j, pairs over k ----
    h2 E[24];
#pragma unroll
    for (int k = 0; k < T; k += 2) {
        const int i0 = w ? (j * T + k)     : (k * T + j);
        const int i1 = w ? (j * T + k + 1) : ((k + 1) * T + j);
        h2 e;
        e[0] = (_Float16)exp2f(trans[i0] * LOG2E + ESC);
        e[1] = (_Float16)exp2f(trans[i1] * LOG2E + ESC);
        E[k >> 1] = e;
    }

    const float* ep = em_b + j;
    const int maxoff = (SLEN - 1) * T;

    // ---- init state + initial broadcast ----
    float st, L, pubinit;
    if (w == 0) {
        const float z0 = (start_t[j] + em_b[j]) * LOG2E;
        const float m0 = wave_max(z0);
        st = exp2f(z0 - m0); L = m0;
        pubinit = st;
    } else {
        st = exp2f(end_t[j] * LOG2E); L = 0.f;
        const float vlast = ep[(size_t)(len - 1) * T];
        pubinit = fminf(st * exp2f(vlast * LOG2E), 60000.f);
    }
    unsigned sf[24];
    BCAST24(sf, pubinit)

    // ---- gold path score (forward wave only) ----
    float g = 0.f;
    if (w == 0) {
        for (int i = lane; i < len; i += 64) {
            if (i >= 1) {
                const int tc = tags_b[i];
                const int tp = tags_b[i - 1];
                g += trans[tc * T + tp] + em_b[(size_t)i * T + tc];
            }
        }
        g = wave_sum(g);
    }

    // ---- emission ring (4 deep) ----
    const int dlt = w ? -T : T;
    int off = w ? (len - 2) * T : T;
    auto ldem = [&]() -> float {
        int oc = off;
        oc = oc < 0 ? 0 : oc;
        oc = oc > maxoff ? maxoff : oc;
        const float r = ep[oc];
        off += dlt;
        return r;
    };
    float f0 = ldem(), f1 = ldem(), f2 = ldem(), f3 = ldem();

    auto rescale = [&](float& v) {   // exact pow2, 4-lane probe
        float m = fmaxf(fmaxf(rlane(v, 0), rlane(v, 16)),
                        fmaxf(rlane(v, 32), rlane(v, 47)));
        int e = ((__float_as_int(m) >> 23) & 255) - 127;
        e = e < -64 ? -64 : e;
        v *= __int_as_float((127 - e) << 23);
        L += (float)e;
    };

    auto step = [&](float& fe, bool resc) {
        const float wv = exp2f(fe * LOG2E);
        fe = ldem();
        float a0 = 0.f, a1 = 0.f, a2 = 0.f, a3 = 0.f;
        DOTS48(sf, E, a0, a1, a2, a3)
        float s = (a0 + a1) + (a2 + a3);
        if (w == 0) s *= wv;               // fwd: dest-weight at compute
        if (resc) rescale(s);
        st = s;
        const float pub = fminf(w ? s * wv : s, 60000.f);  // bwd: weight at publish
        BCAST24(sf, pub)
    };

    int rem = steps;
    while (rem >= 4) {
        step(f0, false); step(f1, false); step(f2, false); step(f3, true);
        rem -= 4;
    }
    if (rem > 0) { step(f0, false);
        if (rem > 1) { step(f1, false);
            if (rem > 2) step(f2, false); } }

    // ---- combine in-block: Z = sum_j p_nf[j] * beta_nf[j] ----
    __shared__ float shu[T];
    __shared__ float shL[2];
    if (w == 0) {
        if (lane == 0) shL[0] = L + 8.0f * (float)nf;  // undo folded 2^-8
    } else {
        if (lane < T) shu[lane] = st;
        if (lane == 0) shL[1] = L + 8.0f * (float)nb;
    }
    __syncthreads();
    if (w == 0) {
        const float v  = (lane < T) ? st * shu[lane] : 0.f;
        const float S_ = wave_sum(v);
        const float fwd = (shL[0] + shL[1] + log2f(S_)) * LN2;
        if (lane == 0) {
            const int t0 = tags_b[0];
            const int tl = tags_b[len - 1];
            const float gold = g + start_t[t0] + em_b[t0] + end_t[tl];
            atomicAdd(out, (fwd - gold) * (1.0f / (float)BATCH));
        }
    }
}

extern "C" void kernel_launch(void* const* d_in, const int* in_sizes, int n_in,
                              void* d_out, int out_size, void* d_ws, size_t ws_size,
                              hipStream_t stream) {
    const float* em      = (const float*)d_in[0];
    const int*   tags    = (const int*)  d_in[1];
    const float* mask    = (const float*)d_in[2];
    const float* trans   = (const float*)d_in[3];
    const float* start_t = (const float*)d_in[4];
    const float* end_t   = (const float*)d_in[5];
    float* out = (float*)d_out;

    hipMemsetAsync(out, 0, sizeof(float), stream);
    crf_kernel<<<BATCH, 128, 0, stream>>>(em, tags, mask, trans, start_t, end_t, out);
}